// Round 1
// baseline (151.351 us; speedup 1.0000x reference)
//
#include <hip/hip_runtime.h>

typedef float f32x4 __attribute__((ext_vector_type(4)));
typedef short s16x8 __attribute__((ext_vector_type(8)));

#define MFMA16(a, b, c) __builtin_amdgcn_mfma_f32_16x16x32_bf16((a), (b), (c), 0, 0, 0)

#define B_ 16
#define M_ 6209
#define F_ 256
#define H_ 64
#define J_ 256

static __device__ __forceinline__ unsigned short f2bf(float x) {
    unsigned u = __builtin_bit_cast(unsigned, x);
    unsigned r = u + 0x7fffu + ((u >> 16) & 1u);
    return (unsigned short)(r >> 16);
}
static __device__ __forceinline__ float bf2f(unsigned short h) {
    unsigned u = ((unsigned)h) << 16;
    return __builtin_bit_cast(float, u);
}
static __device__ __forceinline__ void split_bf(float x, unsigned short& hi, unsigned short& lo) {
    hi = f2bf(x);
    lo = f2bf(x - bf2f(hi));
}

// ---------------- S1: mapped_b = input_b @ Wb + bb  (exact fp32) ----------------
__global__ void k_mapped_b(const float* __restrict__ inB, const float* __restrict__ Wb,
                           const float* __restrict__ bb, float* __restrict__ mb) {
    int bj = blockIdx.x;            // 0 .. 16*256-1
    int b = bj >> 8, j = bj & 255;
    __shared__ float row[256];
    int t = threadIdx.x;            // 64 threads, t = h
    const float* src = inB + ((size_t)(b * 256 + j)) * 256;
    for (int i = t; i < 256; i += 64) row[i] = src[i];
    __syncthreads();
    float s = bb[t];
    #pragma unroll 8
    for (int f = 0; f < 256; ++f) s = fmaf(row[f], Wb[f * 64 + t], s);
    mb[(size_t)(b * 256 + j) * 64 + t] = s;
}

// ---------------- S2: pack fragment-ordered B-operand buffers ----------------
// Fragment layout for mfma_f32_16x16x32_bf16 B operand: lane holds
// B[k][n] with n = nf*16 + (lane&15), k = ks*32 + (lane>>4)*8 + jj, jj=0..7.
__global__ void k_pack(const float* __restrict__ mb, const float* __restrict__ Wa,
                       const float* __restrict__ Wc,
                       unsigned short* __restrict__ waf_hi, unsigned short* __restrict__ waf_lo,
                       unsigned short* __restrict__ wcf,
                       unsigned short* __restrict__ mbb_hi, unsigned short* __restrict__ mbb_lo,
                       unsigned short* __restrict__ mbp) {
    int idx = blockIdx.x * 256 + threadIdx.x;
    if (idx < 16384) {                      // WaF: K=256(f), N=64(h), split
        int i = idx;
        int jj = i & 7, lane = (i >> 3) & 63, nf = (i >> 9) & 3, ks = i >> 11;
        int g = lane >> 4, c = lane & 15;
        int f = ks * 32 + g * 8 + jj, h = nf * 16 + c;
        unsigned short hi, lo; split_bf(Wa[f * 64 + h], hi, lo);
        waf_hi[i] = hi; waf_lo[i] = lo;
    } else if (idx < 32768) {               // WcF: K=64(h), N=256(f), single
        int i = idx - 16384;
        int jj = i & 7, lane = (i >> 3) & 63, nf = (i >> 9) & 15, ks = i >> 13;
        int g = lane >> 4, c = lane & 15;
        int h = ks * 32 + g * 8 + jj, f = nf * 16 + c;
        wcf[i] = f2bf(Wc[h * 256 + f]);
    } else if (idx < 32768 + 262144) {      // mbB (QK^T B = mb^T): K=64(h), N=256(j), split
        int i = idx - 32768;
        int jj = i & 7, lane = (i >> 3) & 63, nf = (i >> 9) & 15, ks = (i >> 13) & 1, b = i >> 14;
        int g = lane >> 4, c = lane & 15;
        int h = ks * 32 + g * 8 + jj, j = nf * 16 + c;
        unsigned short hi, lo; split_bf(mb[((size_t)(b * 256 + j)) * 64 + h], hi, lo);
        mbb_hi[i] = hi; mbb_lo[i] = lo;
    } else {                                 // mbP (PV B = mb): K=256(j), N=64(h), single
        int i = idx - (32768 + 262144);
        int jj = i & 7, lane = (i >> 3) & 63, nf = (i >> 9) & 3, ks = (i >> 11) & 7, b = i >> 14;
        int g = lane >> 4, c = lane & 15;
        int j = ks * 32 + g * 8 + jj, h = nf * 16 + c;
        mbp[i] = f2bf(mb[((size_t)(b * 256 + j)) * 64 + h]);
    }
}

// ---------------- Main fused kernel ----------------
// grid: (98 tiles of 64 rows, 16 batches); block: 256 threads = 4 waves, 16 rows/wave.
__global__ __launch_bounds__(256) void k_main(
    const float* __restrict__ A, const float* __restrict__ ba, const float* __restrict__ bc,
    const unsigned short* __restrict__ waf_hi, const unsigned short* __restrict__ waf_lo,
    const unsigned short* __restrict__ wcf,
    const unsigned short* __restrict__ mbb_hi, const unsigned short* __restrict__ mbb_lo,
    const unsigned short* __restrict__ mbp,
    float* __restrict__ out) {
    __shared__ __align__(16) float maS[4][16][68];          // ma / out1 transpose scratch
    __shared__ __align__(16) unsigned short pS[4][16][264]; // P (bf16) transpose scratch

    const int tile = blockIdx.x, b = blockIdx.y;
    const int w = threadIdx.x >> 6, lane = threadIdx.x & 63;
    const int g = lane >> 4, c = lane & 15;
    const int row0 = tile * 64 + w * 16;

    // ---- Phase 1: mapped_a[16][64] via split-bf16 MFMA (3 products) ----
    f32x4 accA[4];
    #pragma unroll
    for (int nf = 0; nf < 4; ++nf) { float v = ba[nf * 16 + c]; accA[nf] = (f32x4){v, v, v, v}; }

    int arow = row0 + c; if (arow > M_ - 1) arow = M_ - 1;   // clamp tail rows (stores masked)
    const float* abase = A + ((size_t)b * M_ + arow) * F_;
    #pragma unroll
    for (int ks = 0; ks < 8; ++ks) {
        const float* ap = abase + ks * 32 + g * 8;
        s16x8 ah, al;
        #pragma unroll
        for (int j = 0; j < 8; ++j) {
            unsigned short hi, lo; split_bf(ap[j], hi, lo);
            ah[j] = (short)hi; al[j] = (short)lo;
        }
        #pragma unroll
        for (int nf = 0; nf < 4; ++nf) {
            const int off = ((ks * 4 + nf) * 64 + lane) << 3;
            const s16x8 bh = *(const s16x8*)(waf_hi + off);
            const s16x8 bl = *(const s16x8*)(waf_lo + off);
            accA[nf] = MFMA16(ah, bh, accA[nf]);
            accA[nf] = MFMA16(ah, bl, accA[nf]);
            accA[nf] = MFMA16(al, bh, accA[nf]);
        }
    }

    // stash ma (acc layout: row=(g*4+r), col=nf*16+c) to LDS for A-fragment re-read
    #pragma unroll
    for (int nf = 0; nf < 4; ++nf)
        #pragma unroll
        for (int r = 0; r < 4; ++r)
            maS[w][g * 4 + r][nf * 16 + c] = accA[nf][r];

    // ---- Phase 2: QK^T (split-bf16): scores[16][256] ----
    s16x8 mh[2], ml[2];
    #pragma unroll
    for (int ks = 0; ks < 2; ++ks) {
        const float* mp = &maS[w][c][ks * 32 + g * 8];
        #pragma unroll
        for (int j = 0; j < 8; ++j) {
            unsigned short hi, lo; split_bf(mp[j], hi, lo);
            mh[ks][j] = (short)hi; ml[ks][j] = (short)lo;
        }
    }
    f32x4 accS[16];
    #pragma unroll
    for (int nf = 0; nf < 16; ++nf) accS[nf] = (f32x4){0.f, 0.f, 0.f, 0.f};
    #pragma unroll
    for (int nf = 0; nf < 16; ++nf) {
        #pragma unroll
        for (int ks = 0; ks < 2; ++ks) {
            const size_t off = ((((size_t)b * 2 + ks) * 16 + nf) * 64 + lane) << 3;
            const s16x8 bh = *(const s16x8*)(mbb_hi + off);
            const s16x8 bl = *(const s16x8*)(mbb_lo + off);
            accS[nf] = MFMA16(mh[ks], bh, accS[nf]);
            accS[nf] = MFMA16(mh[ks], bl, accS[nf]);
            accS[nf] = MFMA16(ml[ks], bh, accS[nf]);
        }
    }

    // ---- Phase 3: row softmax (scale 8 folded into exp2), unnormalized P ----
    const float SC = 11.541560327f;   // 8 * log2(e)
    float rinv[4];
    #pragma unroll
    for (int r = 0; r < 4; ++r) {
        float m = accS[0][r];
        #pragma unroll
        for (int nf = 1; nf < 16; ++nf) m = fmaxf(m, accS[nf][r]);
        m = fmaxf(m, __shfl_xor(m, 1));
        m = fmaxf(m, __shfl_xor(m, 2));
        m = fmaxf(m, __shfl_xor(m, 4));
        m = fmaxf(m, __shfl_xor(m, 8));
        float s = 0.f;
        #pragma unroll
        for (int nf = 0; nf < 16; ++nf) {
            float pv = __builtin_amdgcn_exp2f((accS[nf][r] - m) * SC);
            s += pv;
            pS[w][g * 4 + r][nf * 16 + c] = f2bf(pv);
        }
        s += __shfl_xor(s, 1);
        s += __shfl_xor(s, 2);
        s += __shfl_xor(s, 4);
        s += __shfl_xor(s, 8);
        rinv[r] = 1.f / s;
    }

    // ---- Phase 4: PV (single bf16), fold 1/rowsum into accumulator ----
    f32x4 acc1[4];
    #pragma unroll
    for (int nf = 0; nf < 4; ++nf) acc1[nf] = (f32x4){0.f, 0.f, 0.f, 0.f};
    #pragma unroll
    for (int ks = 0; ks < 8; ++ks) {
        const s16x8 pa = *(const s16x8*)&pS[w][c][ks * 32 + g * 8];
        #pragma unroll
        for (int nf = 0; nf < 4; ++nf) {
            const size_t off = ((((size_t)b * 8 + ks) * 4 + nf) * 64 + lane) << 3;
            const s16x8 vb = *(const s16x8*)(mbp + off);
            acc1[nf] = MFMA16(pa, vb, acc1[nf]);
        }
    }
    #pragma unroll
    for (int nf = 0; nf < 4; ++nf)
        #pragma unroll
        for (int r = 0; r < 4; ++r)
            maS[w][g * 4 + r][nf * 16 + c] = acc1[nf][r] * rinv[r];

    // ---- Phase 5: final projection out1 @ Wc + bc ----
    s16x8 oh[2];
    #pragma unroll
    for (int ks = 0; ks < 2; ++ks) {
        const float* op = &maS[w][c][ks * 32 + g * 8];
        #pragma unroll
        for (int j = 0; j < 8; ++j) oh[ks][j] = (short)f2bf(op[j]);
    }
    f32x4 accF[16];
    #pragma unroll
    for (int nf = 0; nf < 16; ++nf) { float v = bc[nf * 16 + c]; accF[nf] = (f32x4){v, v, v, v}; }
    #pragma unroll
    for (int nf = 0; nf < 16; ++nf) {
        #pragma unroll
        for (int ks = 0; ks < 2; ++ks) {
            const s16x8 wb = *(const s16x8*)(wcf + (((ks * 16 + nf) * 64 + lane) << 3));
            accF[nf] = MFMA16(oh[ks], wb, accF[nf]);
        }
    }
    #pragma unroll
    for (int nf = 0; nf < 16; ++nf) {
        #pragma unroll
        for (int r = 0; r < 4; ++r) {
            int row = row0 + g * 4 + r;
            if (row < M_) out[((size_t)b * M_ + row) * F_ + nf * 16 + c] = accF[nf][r];
        }
    }
}

extern "C" void kernel_launch(void* const* d_in, const int* in_sizes, int n_in,
                              void* d_out, int out_size, void* d_ws, size_t ws_size,
                              hipStream_t stream) {
    (void)in_sizes; (void)n_in; (void)out_size; (void)ws_size;
    const float* inA = (const float*)d_in[0];
    const float* inB = (const float*)d_in[1];
    const float* Wa  = (const float*)d_in[2];
    const float* ba  = (const float*)d_in[3];
    const float* Wb  = (const float*)d_in[4];
    const float* bb  = (const float*)d_in[5];
    const float* Wc  = (const float*)d_in[6];
    const float* bc  = (const float*)d_in[7];
    float* out = (float*)d_out;

    char* ws = (char*)d_ws;
    float* mb              = (float*)ws;                          // 1,048,576 B
    unsigned short* waf_hi = (unsigned short*)(ws + 1048576);     //    32,768 B
    unsigned short* waf_lo = (unsigned short*)(ws + 1081344);     //    32,768 B
    unsigned short* wcf    = (unsigned short*)(ws + 1114112);     //    32,768 B
    unsigned short* mbb_hi = (unsigned short*)(ws + 1146880);     //   524,288 B
    unsigned short* mbb_lo = (unsigned short*)(ws + 1671168);     //   524,288 B
    unsigned short* mbp    = (unsigned short*)(ws + 2195456);     //   524,288 B  (end ~2.72 MB)

    hipLaunchKernelGGL(k_mapped_b, dim3(B_ * J_), dim3(64), 0, stream, inB, Wb, bb, mb);
    hipLaunchKernelGGL(k_pack, dim3((557056 + 255) / 256), dim3(256), 0, stream,
                       mb, Wa, Wc, waf_hi, waf_lo, wcf, mbb_hi, mbb_lo, mbp);
    hipLaunchKernelGGL(k_main, dim3(98, 16), dim3(256), 0, stream,
                       inA, ba, bc, waf_hi, waf_lo, wcf, mbb_hi, mbb_lo, mbp, out);
}

// Round 2
// 111.921 us; speedup vs baseline: 1.3523x; 1.3523x over previous
//
#include <hip/hip_runtime.h>

typedef float f32x4 __attribute__((ext_vector_type(4)));
typedef short s16x8 __attribute__((ext_vector_type(8)));

#define MFMA16(a, b, c) __builtin_amdgcn_mfma_f32_16x16x32_bf16((a), (b), (c), 0, 0, 0)

#define B_ 16
#define M_ 6209
#define F_ 256
#define H_ 64
#define J_ 256

static __device__ __forceinline__ unsigned short f2bf(float x) {
    unsigned u = __builtin_bit_cast(unsigned, x);
    unsigned r = u + 0x7fffu + ((u >> 16) & 1u);
    return (unsigned short)(r >> 16);
}
static __device__ __forceinline__ float bf2f(unsigned short h) {
    unsigned u = ((unsigned)h) << 16;
    return __builtin_bit_cast(float, u);
}
static __device__ __forceinline__ void split_bf(float x, unsigned short& hi, unsigned short& lo) {
    hi = f2bf(x);
    lo = f2bf(x - bf2f(hi));
}

// ---------------- S1: mapped_b = input_b @ Wb + bb  (exact fp32) ----------------
__global__ void k_mapped_b(const float* __restrict__ inB, const float* __restrict__ Wb,
                           const float* __restrict__ bb, float* __restrict__ mb) {
    int bj = blockIdx.x;            // 0 .. 16*256-1
    int b = bj >> 8, j = bj & 255;
    __shared__ float row[256];
    int t = threadIdx.x;            // 64 threads, t = h
    const float* src = inB + ((size_t)(b * 256 + j)) * 256;
    for (int i = t; i < 256; i += 64) row[i] = src[i];
    __syncthreads();
    float s = bb[t];
    #pragma unroll 8
    for (int f = 0; f < 256; ++f) s = fmaf(row[f], Wb[f * 64 + t], s);
    mb[(size_t)(b * 256 + j) * 64 + t] = s;
}

// ---------------- S2: pack fragment-ordered B-operand buffers ----------------
// Fragment layout for mfma_f32_16x16x32_bf16 B operand: lane holds
// B[k][n] with n = nf*16 + (lane&15), k = ks*32 + (lane>>4)*8 + jj, jj=0..7.
__global__ void k_pack(const float* __restrict__ mb, const float* __restrict__ Wa,
                       const float* __restrict__ Wc,
                       unsigned short* __restrict__ waf_hi, unsigned short* __restrict__ waf_lo,
                       unsigned short* __restrict__ wcf,
                       unsigned short* __restrict__ mbb_hi, unsigned short* __restrict__ mbb_lo,
                       unsigned short* __restrict__ mbp) {
    int idx = blockIdx.x * 256 + threadIdx.x;
    if (idx < 16384) {                      // WaF: K=256(f), N=64(h), split
        int i = idx;
        int jj = i & 7, lane = (i >> 3) & 63, nf = (i >> 9) & 3, ks = i >> 11;
        int g = lane >> 4, c = lane & 15;
        int f = ks * 32 + g * 8 + jj, h = nf * 16 + c;
        unsigned short hi, lo; split_bf(Wa[f * 64 + h], hi, lo);
        waf_hi[i] = hi; waf_lo[i] = lo;
    } else if (idx < 32768) {               // WcF: K=64(h), N=256(f), single
        int i = idx - 16384;
        int jj = i & 7, lane = (i >> 3) & 63, nf = (i >> 9) & 15, ks = i >> 13;
        int g = lane >> 4, c = lane & 15;
        int h = ks * 32 + g * 8 + jj, f = nf * 16 + c;
        wcf[i] = f2bf(Wc[h * 256 + f]);
    } else if (idx < 32768 + 262144) {      // mbB (QK^T B = mb^T): K=64(h), N=256(j), split
        int i = idx - 32768;
        int jj = i & 7, lane = (i >> 3) & 63, nf = (i >> 9) & 15, ks = (i >> 13) & 1, b = i >> 14;
        int g = lane >> 4, c = lane & 15;
        int h = ks * 32 + g * 8 + jj, j = nf * 16 + c;
        unsigned short hi, lo; split_bf(mb[((size_t)(b * 256 + j)) * 64 + h], hi, lo);
        mbb_hi[i] = hi; mbb_lo[i] = lo;
    } else {                                 // mbP (PV B = mb): K=256(j), N=64(h), single
        int i = idx - (32768 + 262144);
        int jj = i & 7, lane = (i >> 3) & 63, nf = (i >> 9) & 3, ks = (i >> 11) & 7, b = i >> 14;
        int g = lane >> 4, c = lane & 15;
        int j = ks * 32 + g * 8 + jj, h = nf * 16 + c;
        mbp[i] = f2bf(mb[((size_t)(b * 256 + j)) * 64 + h]);
    }
}

// ---------------- Main fused kernel ----------------
// grid: (389 tiles of 16 rows, 16 batches); block: 256 threads = 4 waves.
// Work split ACROSS waves (not replicated): wave w owns h-chunk w (P1),
// j-quarter w (P2 QK^T + partial softmax + P4 PV partial), f-quarter w (P5).
__global__ __launch_bounds__(256) void k_main(
    const float* __restrict__ A, const float* __restrict__ ba, const float* __restrict__ bc,
    const unsigned short* __restrict__ waf_hi, const unsigned short* __restrict__ waf_lo,
    const unsigned short* __restrict__ wcf,
    const unsigned short* __restrict__ mbb_hi, const unsigned short* __restrict__ mbb_lo,
    const unsigned short* __restrict__ mbp,
    float* __restrict__ out) {
    __shared__ __align__(16) float maS[16][76];            // mapped_a fp32 (padded)
    __shared__ __align__(16) unsigned short pS[16][264];   // P bf16
    __shared__ float pmaxS[4][16];                         // per-quarter row max (raw logits)
    __shared__ float psumS[4][16];                         // per-quarter row sum (local-max scaled)
    __shared__ __align__(16) float o1S[4][16][76];         // PV partials (rescaled)

    const int tile = blockIdx.x, b = blockIdx.y;
    const int w = threadIdx.x >> 6, lane = threadIdx.x & 63;
    const int g = lane >> 4, c = lane & 15;
    const int row0 = tile * 16;
    const float SC = 11.541560327f;   // 8 * log2(e)

    // ---- Phase 1: mapped_a[16 rows][h-chunk w*16..w*16+16) via split MFMA ----
    f32x4 accA;
    { float v = ba[w * 16 + c]; accA = (f32x4){v, v, v, v}; }
    int arow = row0 + c; if (arow > M_ - 1) arow = M_ - 1;   // clamp tail (stores masked)
    const float* abase = A + ((size_t)b * M_ + arow) * F_;
    #pragma unroll
    for (int ks = 0; ks < 8; ++ks) {
        const float* ap = abase + ks * 32 + g * 8;
        s16x8 ah, al;
        #pragma unroll
        for (int j = 0; j < 8; ++j) {
            unsigned short hi, lo; split_bf(ap[j], hi, lo);
            ah[j] = (short)hi; al[j] = (short)lo;
        }
        const int off = ((ks * 4 + w) * 64 + lane) << 3;
        const s16x8 bh = *(const s16x8*)(waf_hi + off);
        const s16x8 bl = *(const s16x8*)(waf_lo + off);
        accA = MFMA16(ah, bh, accA);
        accA = MFMA16(ah, bl, accA);
        accA = MFMA16(al, bh, accA);
    }
    #pragma unroll
    for (int r = 0; r < 4; ++r)
        maS[g * 4 + r][w * 16 + c] = accA[r];
    __syncthreads();

    // ---- Phase 2: QK^T for j-quarter w + partial softmax ----
    s16x8 mh[2], ml[2];
    #pragma unroll
    for (int ks = 0; ks < 2; ++ks) {
        const float* mp = &maS[c][ks * 32 + g * 8];
        #pragma unroll
        for (int j = 0; j < 8; ++j) {
            unsigned short hi, lo; split_bf(mp[j], hi, lo);
            mh[ks][j] = (short)hi; ml[ks][j] = (short)lo;
        }
    }
    f32x4 accS[4];
    #pragma unroll
    for (int nfl = 0; nfl < 4; ++nfl) accS[nfl] = (f32x4){0.f, 0.f, 0.f, 0.f};
    #pragma unroll
    for (int nfl = 0; nfl < 4; ++nfl) {
        const int nf = w * 4 + nfl;
        #pragma unroll
        for (int ks = 0; ks < 2; ++ks) {
            const size_t off = ((((size_t)b * 2 + ks) * 16 + nf) * 64 + lane) << 3;
            const s16x8 bh = *(const s16x8*)(mbb_hi + off);
            const s16x8 bl = *(const s16x8*)(mbb_lo + off);
            accS[nfl] = MFMA16(mh[ks], bh, accS[nfl]);
            accS[nfl] = MFMA16(mh[ks], bl, accS[nfl]);
            accS[nfl] = MFMA16(ml[ks], bh, accS[nfl]);
        }
    }
    // partial softmax over this quarter (local max, local sum); store P (local scale)
    #pragma unroll
    for (int r = 0; r < 4; ++r) {
        float m = accS[0][r];
        #pragma unroll
        for (int nfl = 1; nfl < 4; ++nfl) m = fmaxf(m, accS[nfl][r]);
        m = fmaxf(m, __shfl_xor(m, 1));
        m = fmaxf(m, __shfl_xor(m, 2));
        m = fmaxf(m, __shfl_xor(m, 4));
        m = fmaxf(m, __shfl_xor(m, 8));
        float s = 0.f;
        #pragma unroll
        for (int nfl = 0; nfl < 4; ++nfl) {
            float pv = __builtin_amdgcn_exp2f((accS[nfl][r] - m) * SC);
            s += pv;
            pS[g * 4 + r][w * 64 + nfl * 16 + c] = f2bf(pv);
        }
        s += __shfl_xor(s, 1);
        s += __shfl_xor(s, 2);
        s += __shfl_xor(s, 4);
        s += __shfl_xor(s, 8);
        if (c == 0) { pmaxS[w][g * 4 + r] = m; psumS[w][g * 4 + r] = s; }
    }
    __syncthreads();

    // ---- Phase 4: PV partial over j-quarter w, rescaled to global max ----
    s16x8 pa[2];
    #pragma unroll
    for (int ksl = 0; ksl < 2; ++ksl)
        pa[ksl] = *(const s16x8*)&pS[c][w * 64 + ksl * 32 + g * 8];
    f32x4 acc1[4];
    #pragma unroll
    for (int nfh = 0; nfh < 4; ++nfh) acc1[nfh] = (f32x4){0.f, 0.f, 0.f, 0.f};
    #pragma unroll
    for (int nfh = 0; nfh < 4; ++nfh) {
        #pragma unroll
        for (int ksl = 0; ksl < 2; ++ksl) {
            const int ksg = w * 2 + ksl;
            const size_t off = ((((size_t)b * 8 + ksg) * 4 + nfh) * 64 + lane) << 3;
            const s16x8 vb = *(const s16x8*)(mbp + off);
            acc1[nfh] = MFMA16(pa[ksl], vb, acc1[nfh]);
        }
    }
    // rescale partial by exp(local_max - global_max) per row, write to LDS
    float sw[4];
    #pragma unroll
    for (int r = 0; r < 4; ++r) {
        const int row = g * 4 + r;
        float m0 = pmaxS[0][row], m1 = pmaxS[1][row], m2 = pmaxS[2][row], m3 = pmaxS[3][row];
        float mg = fmaxf(fmaxf(m0, m1), fmaxf(m2, m3));
        sw[r] = __builtin_amdgcn_exp2f((pmaxS[w][row] - mg) * SC);
    }
    #pragma unroll
    for (int nfh = 0; nfh < 4; ++nfh)
        #pragma unroll
        for (int r = 0; r < 4; ++r)
            o1S[w][g * 4 + r][nfh * 16 + c] = acc1[nfh][r] * sw[r];
    __syncthreads();

    // ---- Phase 5: final projection (f-quarter w): out = out1 @ Wc + bc ----
    // row-sum reciprocal for row c (A-fragment row of this lane)
    float rinv;
    {
        float m0 = pmaxS[0][c], m1 = pmaxS[1][c], m2 = pmaxS[2][c], m3 = pmaxS[3][c];
        float mg = fmaxf(fmaxf(m0, m1), fmaxf(m2, m3));
        float s = psumS[0][c] * __builtin_amdgcn_exp2f((m0 - mg) * SC)
                + psumS[1][c] * __builtin_amdgcn_exp2f((m1 - mg) * SC)
                + psumS[2][c] * __builtin_amdgcn_exp2f((m2 - mg) * SC)
                + psumS[3][c] * __builtin_amdgcn_exp2f((m3 - mg) * SC);
        rinv = 1.f / s;
    }
    s16x8 oh[2];
    #pragma unroll
    for (int ks = 0; ks < 2; ++ks) {
        #pragma unroll
        for (int j = 0; j < 8; ++j) {
            const int k = ks * 32 + g * 8 + j;
            float v = (o1S[0][c][k] + o1S[1][c][k] + o1S[2][c][k] + o1S[3][c][k]) * rinv;
            oh[ks][j] = (short)f2bf(v);
        }
    }
    f32x4 accF[4];
    #pragma unroll
    for (int nfl = 0; nfl < 4; ++nfl) { float v = bc[w * 64 + nfl * 16 + c]; accF[nfl] = (f32x4){v, v, v, v}; }
    #pragma unroll
    for (int nfl = 0; nfl < 4; ++nfl) {
        #pragma unroll
        for (int ks = 0; ks < 2; ++ks) {
            const int nf = w * 4 + nfl;
            const s16x8 wb = *(const s16x8*)(wcf + (((ks * 16 + nf) * 64 + lane) << 3));
            accF[nfl] = MFMA16(oh[ks], wb, accF[nfl]);
        }
    }
    #pragma unroll
    for (int nfl = 0; nfl < 4; ++nfl) {
        #pragma unroll
        for (int r = 0; r < 4; ++r) {
            const int row = row0 + g * 4 + r;
            if (row < M_) out[((size_t)b * M_ + row) * F_ + w * 64 + nfl * 16 + c] = accF[nfl][r];
        }
    }
}

extern "C" void kernel_launch(void* const* d_in, const int* in_sizes, int n_in,
                              void* d_out, int out_size, void* d_ws, size_t ws_size,
                              hipStream_t stream) {
    (void)in_sizes; (void)n_in; (void)out_size; (void)ws_size;
    const float* inA = (const float*)d_in[0];
    const float* inB = (const float*)d_in[1];
    const float* Wa  = (const float*)d_in[2];
    const float* ba  = (const float*)d_in[3];
    const float* Wb  = (const float*)d_in[4];
    const float* bb  = (const float*)d_in[5];
    const float* Wc  = (const float*)d_in[6];
    const float* bc  = (const float*)d_in[7];
    float* out = (float*)d_out;

    char* ws = (char*)d_ws;
    float* mb              = (float*)ws;                          // 1,048,576 B
    unsigned short* waf_hi = (unsigned short*)(ws + 1048576);     //    32,768 B
    unsigned short* waf_lo = (unsigned short*)(ws + 1081344);     //    32,768 B
    unsigned short* wcf    = (unsigned short*)(ws + 1114112);     //    32,768 B
    unsigned short* mbb_hi = (unsigned short*)(ws + 1146880);     //   524,288 B
    unsigned short* mbb_lo = (unsigned short*)(ws + 1671168);     //   524,288 B
    unsigned short* mbp    = (unsigned short*)(ws + 2195456);     //   524,288 B  (end ~2.72 MB)

    hipLaunchKernelGGL(k_mapped_b, dim3(B_ * J_), dim3(64), 0, stream, inB, Wb, bb, mb);
    hipLaunchKernelGGL(k_pack, dim3((557056 + 255) / 256), dim3(256), 0, stream,
                       mb, Wa, Wc, waf_hi, waf_lo, wcf, mbb_hi, mbb_lo, mbp);
    hipLaunchKernelGGL(k_main, dim3((M_ + 15) / 16, B_), dim3(256), 0, stream,
                       inA, ba, bc, waf_hi, waf_lo, wcf, mbb_hi, mbb_lo, mbp, out);
}

// Round 3
// 98.058 us; speedup vs baseline: 1.5435x; 1.1414x over previous
//
#include <hip/hip_runtime.h>

typedef float f32x4 __attribute__((ext_vector_type(4)));
typedef short s16x8 __attribute__((ext_vector_type(8)));

#define MFMA16(a, b, c) __builtin_amdgcn_mfma_f32_16x16x32_bf16((a), (b), (c), 0, 0, 0)

#define B_ 16
#define M_ 6209
#define F_ 256
#define H_ 64
#define J_ 256

static __device__ __forceinline__ unsigned short f2bf(float x) {
    unsigned u = __builtin_bit_cast(unsigned, x);
    unsigned r = u + 0x7fffu + ((u >> 16) & 1u);
    return (unsigned short)(r >> 16);
}
static __device__ __forceinline__ float bf2f(unsigned short h) {
    unsigned u = ((unsigned)h) << 16;
    return __builtin_bit_cast(float, u);
}
static __device__ __forceinline__ void split_bf(float x, unsigned short& hi, unsigned short& lo) {
    hi = f2bf(x);
    lo = f2bf(x - bf2f(hi));
}

// ---------------- S1: mapped_b = input_b @ Wb + bb  (exact fp32) ----------------
__global__ void k_mapped_b(const float* __restrict__ inB, const float* __restrict__ Wb,
                           const float* __restrict__ bb, float* __restrict__ mb) {
    int bj = blockIdx.x;            // 0 .. 16*256-1
    int b = bj >> 8, j = bj & 255;
    __shared__ float row[256];
    int t = threadIdx.x;            // 64 threads, t = h
    const float* src = inB + ((size_t)(b * 256 + j)) * 256;
    for (int i = t; i < 256; i += 64) row[i] = src[i];
    __syncthreads();
    float s = bb[t];
    #pragma unroll 8
    for (int f = 0; f < 256; ++f) s = fmaf(row[f], Wb[f * 64 + t], s);
    mb[(size_t)(b * 256 + j) * 64 + t] = s;
}

// ---------------- S2: pack fragment-ordered B-operand buffers ----------------
// Fragment layout for mfma_f32_16x16x32_bf16 B operand: lane holds
// B[k][n] with n = nf*16 + (lane&15), k = ks*32 + (lane>>4)*8 + jj, jj=0..7.
__global__ void k_pack(const float* __restrict__ mb, const float* __restrict__ Wa,
                       const float* __restrict__ Wc,
                       unsigned short* __restrict__ waf_hi, unsigned short* __restrict__ waf_lo,
                       unsigned short* __restrict__ wcf,
                       unsigned short* __restrict__ mbb_hi, unsigned short* __restrict__ mbb_lo,
                       unsigned short* __restrict__ mbp) {
    int idx = blockIdx.x * 256 + threadIdx.x;
    if (idx < 16384) {                      // WaF: K=256(f), N=64(h), split
        int i = idx;
        int jj = i & 7, lane = (i >> 3) & 63, nf = (i >> 9) & 3, ks = i >> 11;
        int g = lane >> 4, c = lane & 15;
        int f = ks * 32 + g * 8 + jj, h = nf * 16 + c;
        unsigned short hi, lo; split_bf(Wa[f * 64 + h], hi, lo);
        waf_hi[i] = hi; waf_lo[i] = lo;
    } else if (idx < 32768) {               // WcF: K=64(h), N=256(f), single
        int i = idx - 16384;
        int jj = i & 7, lane = (i >> 3) & 63, nf = (i >> 9) & 15, ks = i >> 13;
        int g = lane >> 4, c = lane & 15;
        int h = ks * 32 + g * 8 + jj, f = nf * 16 + c;
        wcf[i] = f2bf(Wc[h * 256 + f]);
    } else if (idx < 32768 + 262144) {      // mbB (QK^T B = mb^T): K=64(h), N=256(j), split
        int i = idx - 32768;
        int jj = i & 7, lane = (i >> 3) & 63, nf = (i >> 9) & 15, ks = (i >> 13) & 1, b = i >> 14;
        int g = lane >> 4, c = lane & 15;
        int h = ks * 32 + g * 8 + jj, j = nf * 16 + c;
        unsigned short hi, lo; split_bf(mb[((size_t)(b * 256 + j)) * 64 + h], hi, lo);
        mbb_hi[i] = hi; mbb_lo[i] = lo;
    } else {                                 // mbP (PV B = mb): K=256(j), N=64(h), single
        int i = idx - (32768 + 262144);
        int jj = i & 7, lane = (i >> 3) & 63, nf = (i >> 9) & 3, ks = (i >> 11) & 7, b = i >> 14;
        int g = lane >> 4, c = lane & 15;
        int j = ks * 32 + g * 8 + jj, h = nf * 16 + c;
        mbp[i] = f2bf(mb[((size_t)(b * 256 + j)) * 64 + h]);
    }
}

// ---------------- Main fused kernel ----------------
// grid: (98 tiles of 64 rows, 16 batches); block: 256 threads = 4 waves.
// P1: wave w owns row-quarter w (A split once, no redundancy) -> split ma to LDS
// P2: wave w owns j-quarter (all 64 rows), LDS ma frags, accS[4][4]
// P3: wave w owns h-chunk w for PV (K=256 from LDS P)
// P4: wave w owns f-quarter of projection
__global__ __launch_bounds__(256, 3) void k_main(
    const float* __restrict__ A, const float* __restrict__ ba, const float* __restrict__ bc,
    const unsigned short* __restrict__ waf_hi, const unsigned short* __restrict__ waf_lo,
    const unsigned short* __restrict__ wcf,
    const unsigned short* __restrict__ mbb_hi, const unsigned short* __restrict__ mbb_lo,
    const unsigned short* __restrict__ mbp,
    float* __restrict__ out) {
    __shared__ __align__(16) unsigned short mahS[64 * 64];   // split ma hi (8 KB), aliased by o1S
    __shared__ __align__(16) unsigned short malS[64 * 64];   // split ma lo (8 KB)
    __shared__ __align__(16) unsigned short pS[64 * 256];    // P bf16 (32 KB)
    __shared__ float pmaxS[4][64];
    __shared__ float psumS[4][64];
    unsigned short* o1S = mahS;   // alias: mahS dead after P2 (guarded by sync2<sync3)

    const int tile = blockIdx.x, b = blockIdx.y;
    const int w = threadIdx.x >> 6, lane = threadIdx.x & 63;
    const int g = lane >> 4, c = lane & 15;
    const int row0 = tile * 64;
    const float SC = 11.541560327f;   // 8 * log2(e)

    // XOR-swizzled u16 index (row-major, stride in u16; xor spreads banks, keeps 8-u16 chunks contiguous)
    #define SWZ64(row, k)  (((row) * 64 + (k)) ^ (((row) & 7) << 3))
    #define SWZ256(row, k) (((row) * 256 + (k)) ^ (((row) & 7) << 3))

    // ---- P1: ma rows [w*16, w*16+16), all 64 h; split-bf16 triple MFMA ----
    f32x4 accA[4];
    #pragma unroll
    for (int nf = 0; nf < 4; ++nf) { float v = ba[nf * 16 + c]; accA[nf] = (f32x4){v, v, v, v}; }
    int arow = row0 + w * 16 + c; if (arow > M_ - 1) arow = M_ - 1;   // clamp tail (stores masked)
    const float* abase = A + ((size_t)b * M_ + arow) * F_;
    #pragma unroll
    for (int ks = 0; ks < 8; ++ks) {
        const f32x4 a0 = *(const f32x4*)(abase + ks * 32 + g * 8);
        const f32x4 a1 = *(const f32x4*)(abase + ks * 32 + g * 8 + 4);
        s16x8 ah, al;
        #pragma unroll
        for (int j = 0; j < 4; ++j) {
            unsigned short hi, lo;
            split_bf(a0[j], hi, lo); ah[j] = (short)hi; al[j] = (short)lo;
            split_bf(a1[j], hi, lo); ah[4 + j] = (short)hi; al[4 + j] = (short)lo;
        }
        #pragma unroll
        for (int nf = 0; nf < 4; ++nf) {
            const int off = ((ks * 4 + nf) * 64 + lane) << 3;
            const s16x8 bh = *(const s16x8*)(waf_hi + off);
            const s16x8 bl = *(const s16x8*)(waf_lo + off);
            accA[nf] = MFMA16(ah, bh, accA[nf]);
            accA[nf] = MFMA16(ah, bl, accA[nf]);
            accA[nf] = MFMA16(al, bh, accA[nf]);
        }
    }
    // write split ma (hi/lo) to LDS; C/D layout: row=g*4+r, col=nf*16+c
    #pragma unroll
    for (int nf = 0; nf < 4; ++nf) {
        #pragma unroll
        for (int r = 0; r < 4; ++r) {
            const int row = w * 16 + g * 4 + r;
            unsigned short hi, lo; split_bf(accA[nf][r], hi, lo);
            mahS[SWZ64(row, nf * 16 + c)] = hi;
            malS[SWZ64(row, nf * 16 + c)] = lo;
        }
    }
    __syncthreads();   // 1: mahS/malS ready

    // ---- P2: QK^T j-quarter w, all 64 rows ----
    f32x4 accS[4][4];   // [nfl][rg]
    #pragma unroll
    for (int nfl = 0; nfl < 4; ++nfl)
        #pragma unroll
        for (int rg = 0; rg < 4; ++rg) accS[nfl][rg] = (f32x4){0.f, 0.f, 0.f, 0.f};
    #pragma unroll
    for (int nfl = 0; nfl < 4; ++nfl) {
        const int nf = w * 4 + nfl;
        const size_t off0 = ((((size_t)b * 2 + 0) * 16 + nf) * 64 + lane) << 3;
        const size_t off1 = ((((size_t)b * 2 + 1) * 16 + nf) * 64 + lane) << 3;
        const s16x8 bh0 = *(const s16x8*)(mbb_hi + off0);
        const s16x8 bl0 = *(const s16x8*)(mbb_lo + off0);
        const s16x8 bh1 = *(const s16x8*)(mbb_hi + off1);
        const s16x8 bl1 = *(const s16x8*)(mbb_lo + off1);
        #pragma unroll
        for (int rg = 0; rg < 4; ++rg) {
            const int row = rg * 16 + c;
            const s16x8 mh0 = *(const s16x8*)&mahS[SWZ64(row, g * 8)];
            const s16x8 mh1 = *(const s16x8*)&mahS[SWZ64(row, 32 + g * 8)];
            const s16x8 ml0 = *(const s16x8*)&malS[SWZ64(row, g * 8)];
            const s16x8 ml1 = *(const s16x8*)&malS[SWZ64(row, 32 + g * 8)];
            f32x4 acc = accS[nfl][rg];
            acc = MFMA16(mh0, bh0, acc);
            acc = MFMA16(mh1, bh1, acc);
            acc = MFMA16(mh0, bl0, acc);
            acc = MFMA16(mh1, bl1, acc);
            acc = MFMA16(ml0, bh0, acc);
            acc = MFMA16(ml1, bh1, acc);
            accS[nfl][rg] = acc;
        }
    }
    // local (quarter) max per row -> LDS
    #pragma unroll
    for (int rg = 0; rg < 4; ++rg) {
        #pragma unroll
        for (int r = 0; r < 4; ++r) {
            float m = accS[0][rg][r];
            #pragma unroll
            for (int nfl = 1; nfl < 4; ++nfl) m = fmaxf(m, accS[nfl][rg][r]);
            m = fmaxf(m, __shfl_xor(m, 1));
            m = fmaxf(m, __shfl_xor(m, 2));
            m = fmaxf(m, __shfl_xor(m, 4));
            m = fmaxf(m, __shfl_xor(m, 8));
            if (c == 0) pmaxS[w][rg * 16 + g * 4 + r] = m;
        }
    }
    __syncthreads();   // 2: pmaxS ready (accS stays live in VGPRs)
    // global max, P = exp2 on global scale, quarter sums
    #pragma unroll
    for (int rg = 0; rg < 4; ++rg) {
        #pragma unroll
        for (int r = 0; r < 4; ++r) {
            const int row = rg * 16 + g * 4 + r;
            const float mg = fmaxf(fmaxf(pmaxS[0][row], pmaxS[1][row]),
                                   fmaxf(pmaxS[2][row], pmaxS[3][row]));
            float s = 0.f;
            #pragma unroll
            for (int nfl = 0; nfl < 4; ++nfl) {
                const float pv = __builtin_amdgcn_exp2f((accS[nfl][rg][r] - mg) * SC);
                s += pv;
                pS[SWZ256(row, w * 64 + nfl * 16 + c)] = f2bf(pv);
            }
            s += __shfl_xor(s, 1);
            s += __shfl_xor(s, 2);
            s += __shfl_xor(s, 4);
            s += __shfl_xor(s, 8);
            if (c == 0) psumS[w][row] = s;
        }
    }
    __syncthreads();   // 3: pS + psumS ready; mahS (o1S alias) now safely dead

    // ---- P3: PV h-chunk w, K=256 from LDS P ----
    s16x8 vb[8];
    #pragma unroll
    for (int ks = 0; ks < 8; ++ks) {
        const size_t off = ((((size_t)b * 8 + ks) * 4 + w) * 64 + lane) << 3;
        vb[ks] = *(const s16x8*)(mbp + off);
    }
    #pragma unroll
    for (int rg = 0; rg < 4; ++rg) {
        f32x4 acc = (f32x4){0.f, 0.f, 0.f, 0.f};
        #pragma unroll
        for (int ks = 0; ks < 8; ++ks) {
            const s16x8 pa = *(const s16x8*)&pS[SWZ256(rg * 16 + c, ks * 32 + g * 8)];
            acc = MFMA16(pa, vb[ks], acc);
        }
        #pragma unroll
        for (int r = 0; r < 4; ++r) {
            const int row = rg * 16 + g * 4 + r;
            const float s = psumS[0][row] + psumS[1][row] + psumS[2][row] + psumS[3][row];
            o1S[SWZ64(row, w * 16 + c)] = f2bf(acc[r] / s);
        }
    }
    __syncthreads();   // 4: o1S ready

    // ---- P4: projection f-quarter w ----
    s16x8 wb[4][2];
    float bcv[4];
    #pragma unroll
    for (int nfl = 0; nfl < 4; ++nfl) {
        const int nf = w * 4 + nfl;
        wb[nfl][0] = *(const s16x8*)(wcf + (((0 * 16 + nf) * 64 + lane) << 3));
        wb[nfl][1] = *(const s16x8*)(wcf + (((1 * 16 + nf) * 64 + lane) << 3));
        bcv[nfl] = bc[nf * 16 + c];
    }
    #pragma unroll
    for (int rg = 0; rg < 4; ++rg) {
        const int rowl = rg * 16 + c;
        const s16x8 oh0 = *(const s16x8*)&o1S[SWZ64(rowl, g * 8)];
        const s16x8 oh1 = *(const s16x8*)&o1S[SWZ64(rowl, 32 + g * 8)];
        #pragma unroll
        for (int nfl = 0; nfl < 4; ++nfl) {
            f32x4 acc = (f32x4){bcv[nfl], bcv[nfl], bcv[nfl], bcv[nfl]};
            acc = MFMA16(oh0, wb[nfl][0], acc);
            acc = MFMA16(oh1, wb[nfl][1], acc);
            #pragma unroll
            for (int r = 0; r < 4; ++r) {
                const int row = row0 + rg * 16 + g * 4 + r;
                if (row < M_) out[((size_t)b * M_ + row) * F_ + (w * 4 + nfl) * 16 + c] = acc[r];
            }
        }
    }
    #undef SWZ64
    #undef SWZ256
}

extern "C" void kernel_launch(void* const* d_in, const int* in_sizes, int n_in,
                              void* d_out, int out_size, void* d_ws, size_t ws_size,
                              hipStream_t stream) {
    (void)in_sizes; (void)n_in; (void)out_size; (void)ws_size;
    const float* inA = (const float*)d_in[0];
    const float* inB = (const float*)d_in[1];
    const float* Wa  = (const float*)d_in[2];
    const float* ba  = (const float*)d_in[3];
    const float* Wb  = (const float*)d_in[4];
    const float* bb  = (const float*)d_in[5];
    const float* Wc  = (const float*)d_in[6];
    const float* bc  = (const float*)d_in[7];
    float* out = (float*)d_out;

    char* ws = (char*)d_ws;
    float* mb              = (float*)ws;                          // 1,048,576 B
    unsigned short* waf_hi = (unsigned short*)(ws + 1048576);     //    32,768 B
    unsigned short* waf_lo = (unsigned short*)(ws + 1081344);     //    32,768 B
    unsigned short* wcf    = (unsigned short*)(ws + 1114112);     //    32,768 B
    unsigned short* mbb_hi = (unsigned short*)(ws + 1146880);     //   524,288 B
    unsigned short* mbb_lo = (unsigned short*)(ws + 1671168);     //   524,288 B
    unsigned short* mbp    = (unsigned short*)(ws + 2195456);     //   524,288 B  (end ~2.72 MB)

    hipLaunchKernelGGL(k_mapped_b, dim3(B_ * J_), dim3(64), 0, stream, inB, Wb, bb, mb);
    hipLaunchKernelGGL(k_pack, dim3((557056 + 255) / 256), dim3(256), 0, stream,
                       mb, Wa, Wc, waf_hi, waf_lo, wcf, mbb_hi, mbb_lo, mbp);
    hipLaunchKernelGGL(k_main, dim3((M_ + 63) / 64, B_), dim3(256), 0, stream,
                       inA, ba, bc, waf_hi, waf_lo, wcf, mbb_hi, mbb_lo, mbp, out);
}